// Round 1
// baseline (1235.881 us; speedup 1.0000x reference)
//
#include <hip/hip_runtime.h>

// Fold (col2im): cols (16, 64, 128, 128, 3, 3) f32 -> out (16, 64, 128, 128) f32
// stride=1, pad=1, dil=1.
// Gather: out[b,c,h,w] = sum_{i,j} cols[b,c, h+1-i, w+1-j, i, j] (valid indices).
//
// Strategy: 32x32 output tile per 256-thread block. Stage the cols region
// (34 rows x 34 spatial cols x 9 kernel elems = 34x306 f32 = 41.6 KiB LDS)
// with contiguous coalesced loads (per spatial row, the lw*9+k elems are
// contiguous in global). Then each thread sums 9 LDS reads per output, 4
// outputs per thread. LDS read stride 9 (mod 32 banks, gcd(9,32)=1) -> 2
// lanes/bank per wave64 = conflict-free.

#define ROWS 34          // TH + 2
#define ROWE 306         // (TW + 2) * 9

__global__ __launch_bounds__(256, 4) void fold_kernel(
    const float* __restrict__ cols, float* __restrict__ out) {
    __shared__ float smem[ROWS * ROWE];

    const int tid = threadIdx.x;
    const int bx  = blockIdx.x;
    const int tw  = bx & 3;          // 4 tiles along w
    const int th  = (bx >> 2) & 3;   // 4 tiles along h
    const int bc  = bx >> 4;         // 0..1023 (B*C)
    const int h0  = th * 32;
    const int w0  = tw * 32;

    const float* gbase = cols + (size_t)bc * 147456;  // 128*128*9
    // valid flat-element range within a staged row (masks lw out of [0,128))
    const int e_lo = (w0 == 0)  ? 9   : 0;
    const int e_hi = (w0 == 96) ? 297 : ROWE;
    const long woff = (long)(w0 - 1) * 9;

    for (int lr = 0; lr < ROWS; ++lr) {
        const int lh   = h0 - 1 + lr;
        const bool rowv = ((unsigned)lh < 128u);
        const int lhc  = rowv ? lh : 0;
        const float* rowp = gbase + (long)lhc * 1152 + woff;
        #pragma unroll
        for (int e0 = 0; e0 < 512; e0 += 256) {
            const int e = tid + e0;
            if (e < ROWE) {
                float v = 0.0f;
                if (rowv && e >= e_lo && e < e_hi) v = rowp[e];
                smem[lr * ROWE + e] = v;
            }
        }
    }
    __syncthreads();

    const int tx = tid & 31;   // local w
    const int ty = tid >> 5;   // 8 row-groups, 4 rows each
    float* obase = out + (size_t)bc * 16384 + (size_t)h0 * 128 + w0 + tx;

    #pragma unroll
    for (int r = 0; r < 4; ++r) {
        const int hl = ty * 4 + r;   // local h, 0..31
        float acc = 0.0f;
        #pragma unroll
        for (int i = 0; i < 3; ++i) {
            #pragma unroll
            for (int j = 0; j < 3; ++j) {
                // lr = hl + 2 - i in [0,34); e = (tx + 2 - j)*9 + i*3 + j
                acc += smem[(hl + 2 - i) * ROWE + (tx + 2 - j) * 9 + i * 3 + j];
            }
        }
        obase[(size_t)hl * 128] = acc;
    }
}

extern "C" void kernel_launch(void* const* d_in, const int* in_sizes, int n_in,
                              void* d_out, int out_size, void* d_ws, size_t ws_size,
                              hipStream_t stream) {
    const float* cols = (const float*)d_in[0];
    float* out = (float*)d_out;
    // grid: (B*C) * 4 * 4 tiles = 1024 * 16 = 16384 blocks
    dim3 grid(16384), block(256);
    fold_kernel<<<grid, block, 0, stream>>>(cols, out);
}

// Round 2
// 768.385 us; speedup vs baseline: 1.6084x; 1.6084x over previous
//
#include <hip/hip_runtime.h>

// Fold (col2im): cols (16, 64, 128, 128, 3, 3) f32 -> out (16, 64, 128, 128) f32
// stride=1, pad=1, dil=1.
// Gather: out[b,c,h,w] = sum_{i,j} cols[b,c, h+1-i, w+1-j, i, j] (valid indices).
//
// 32x32 output tile per 256-thread block; stage 34 x 306 f32 (41.6 KiB LDS).
// R2 change: branchless, register-batched staging. Loads are unconditional
// (global element index clamped into the valid range -> always in-bounds),
// issued 34-deep per wave from fully unrolled loops, then masked to zero at
// ds_write time. Breaks the per-iteration load->wait->ds_write serialization
// that left the R1 kernel latency-bound at 8.5% of HBM BW.

#define ROWS 34          // TH + 2
#define ROWE 306         // (TW + 2) * 9
#define CHUNK 17

__global__ __launch_bounds__(256, 3) void fold_kernel(
    const float* __restrict__ cols, float* __restrict__ out) {
    __shared__ float smem[ROWS * ROWE];

    const int tid = threadIdx.x;
    const int bx  = blockIdx.x;
    const int tw  = bx & 3;          // 4 tiles along w
    const int th  = (bx >> 2) & 3;   // 4 tiles along h
    const int bc  = bx >> 4;         // 0..1023 (B*C)
    const int h0  = th * 32;
    const int w0  = tw * 32;

    const float* gbase = cols + (size_t)bc * 147456;  // 128*128*9
    // valid flat-element range within a staged row (masks lw out of [0,128))
    const int e_lo = (w0 == 0)  ? 9   : 0;
    const int e_hi = (w0 == 96) ? 297 : ROWE;
    const long woff = (long)(w0 - 1) * 9;

    const int  e0   = tid;            // first staged element this thread owns
    const int  e1   = tid + 256;      // second (only tid < 50 has one)
    const bool has1 = (e1 < ROWE);
    const bool in0  = (e0 >= e_lo) & (e0 < e_hi);
    const bool in1  = (e1 < e_hi);    // e1 >= 256 > e_lo always
    // clamped (always-in-bounds) global element indices for unconditional loads
    const int  es0  = min(max(e0, e_lo), e_hi - 1);
    const int  es1  = min(max(e1, e_lo), e_hi - 1);

    #pragma unroll
    for (int c = 0; c < ROWS; c += CHUNK) {
        float v0[CHUNK], v1[CHUNK];
        #pragma unroll
        for (int k = 0; k < CHUNK; ++k) {
            const int lh  = h0 - 1 + c + k;
            const int lhc = ((unsigned)lh < 128u) ? lh : 0;   // clamp row
            const float* rowp = gbase + (long)lhc * 1152 + woff;
            v0[k] = rowp[es0];
            v1[k] = rowp[es1];
        }
        #pragma unroll
        for (int k = 0; k < CHUNK; ++k) {
            const int  lh   = h0 - 1 + c + k;
            const bool rowv = ((unsigned)lh < 128u);
            smem[(c + k) * ROWE + e0] = (rowv & in0) ? v0[k] : 0.0f;
            if (has1)
                smem[(c + k) * ROWE + e1] = (rowv & in1) ? v1[k] : 0.0f;
        }
    }
    __syncthreads();

    const int tx = tid & 31;   // local w
    const int ty = tid >> 5;   // 8 row-groups, 4 rows each
    float* obase = out + (size_t)bc * 16384 + (size_t)h0 * 128 + w0 + tx;

    #pragma unroll
    for (int r = 0; r < 4; ++r) {
        const int hl = ty * 4 + r;   // local h, 0..31
        float acc = 0.0f;
        #pragma unroll
        for (int i = 0; i < 3; ++i) {
            #pragma unroll
            for (int j = 0; j < 3; ++j) {
                // lr = hl + 2 - i in [0,34); e = (tx + 2 - j)*9 + i*3 + j
                acc += smem[(hl + 2 - i) * ROWE + (tx + 2 - j) * 9 + i * 3 + j];
            }
        }
        obase[(size_t)hl * 128] = acc;
    }
}

extern "C" void kernel_launch(void* const* d_in, const int* in_sizes, int n_in,
                              void* d_out, int out_size, void* d_ws, size_t ws_size,
                              hipStream_t stream) {
    const float* cols = (const float*)d_in[0];
    float* out = (float*)d_out;
    // grid: (B*C) * 4 * 4 tiles = 1024 * 16 = 16384 blocks
    dim3 grid(16384), block(256);
    fold_kernel<<<grid, block, 0, stream>>>(cols, out);
}